// Round 1
// baseline (5505.352 us; speedup 1.0000x reference)
//
#include <hip/hip_runtime.h>
#include <hip/hip_bf16.h>
#include <stdint.h>

typedef __bf16 bf16_t;
typedef __bf16 bf16x8 __attribute__((ext_vector_type(8)));
typedef float f32x4 __attribute__((ext_vector_type(4)));

#define T_STEPS 64
#define BATCH   512
#define NTOKC   512
#define NINP    600
#define NHID    600
#define NBLK    6
#define BSZ     100
#define DK      64
#define ATTD    340
#define DC      32
#define KU_N    384     // 64 (k1) + 300 (u) + pad
#define OUT_KP  608     // NHID padded for dec GEMM K

// workspace layout (bytes), all 16B aligned
#define WS_KU     0u                 // 32768*384*4  = 50331648
#define WS_OUTB   50331648u          // 32768*608*2  = 39845888
#define WS_W1     90177536u          // 512*384*4    = 786432
#define WS_B1     90963968u          // 384*4        = 1536
#define WS_WVWX   90965504u          // 600*300*4    = 720000
#define WS_DECWT  91685504u          // 512*608*2    = 622592  (end ~92.3 MB)

// ---------------- prep kernels (tiny fp32 GEMMs) ----------------

__global__ void prep_wvwx(const float* __restrict__ Wv, const float* __restrict__ Wx,
                          float* __restrict__ WvWx) {
    int idx = blockIdx.x * 256 + threadIdx.x;
    if (idx >= NINP * 300) return;
    int i = idx / 300, c = idx % 300;
    float acc = 0.f;
    for (int a = 0; a < ATTD; a++) acc += Wv[i * ATTD + a] * Wx[a * 300 + c];
    WvWx[i * 300 + c] = acc;
}

__global__ void prep_w1(const float* __restrict__ encW, const float* __restrict__ Wk,
                        const float* __restrict__ WvWx, float* __restrict__ W1) {
    int idx = blockIdx.x * 256 + threadIdx.x;
    if (idx >= NTOKC * KU_N) return;
    int i = idx / KU_N, c = idx % KU_N;
    float acc = 0.f;
    if (c < DK) {
        for (int k = 0; k < NINP; k++) acc += encW[i * NINP + k] * Wk[k * DK + c];
    } else if (c < DK + 300) {
        int cc = c - DK;
        for (int k = 0; k < NINP; k++) acc += encW[i * NINP + k] * WvWx[k * 300 + cc];
    }
    W1[idx] = acc;
}

__global__ void prep_b1(const float* __restrict__ encB, const float* __restrict__ Wk,
                        const float* __restrict__ WvWx, float* __restrict__ b1) {
    int c = blockIdx.x * 256 + threadIdx.x;
    if (c >= KU_N) return;
    float acc = 0.f;
    if (c < DK) {
        for (int k = 0; k < NINP; k++) acc += encB[k] * Wk[k * DK + c];
    } else if (c < DK + 300) {
        int cc = c - DK;
        for (int k = 0; k < NINP; k++) acc += encB[k] * WvWx[k * 300 + cc];
    }
    b1[c] = acc;
}

__global__ void prep_decwt(const float* __restrict__ decW, bf16_t* __restrict__ decWT) {
    int idx = blockIdx.x * 256 + threadIdx.x;
    if (idx >= NTOKC * OUT_KP) return;
    int n = idx / OUT_KP, k = idx % OUT_KP;
    decWT[idx] = (k < NHID) ? (bf16_t)decW[k * NTOKC + n] : (bf16_t)0.f;
}

// ---------------- KU = input @ W1 + b1 (fp32; precision-critical) ----------------
// M=32768, K=512, N=384. BM=128 BN=64 BK=16, 256 thr, 8x4 per-thread tile.

__global__ __launch_bounds__(256) void ku_gemm(const float* __restrict__ A,
                                               const float* __restrict__ W1,
                                               const float* __restrict__ b1,
                                               float* __restrict__ KU) {
    __shared__ float As[16][128];
    __shared__ float Bs[16][64];
    const int tid = threadIdx.x;
    const int m0 = blockIdx.x * 128, n0 = blockIdx.y * 64;
    const int ty = tid >> 4, tx = tid & 15;
    const int bk = tid >> 6, bn = tid & 63;
    float acc[8][4] = {};
    for (int k0 = 0; k0 < NTOKC; k0 += 16) {
#pragma unroll
        for (int ii = 0; ii < 2; ii++) {
            int t2 = tid + ii * 256;
            int ar = t2 >> 2, ac4 = (t2 & 3) << 2;
            float4 raw = *(const float4*)(A + (size_t)(m0 + ar) * NTOKC + k0 + ac4);
            As[ac4 + 0][ar] = raw.x;
            As[ac4 + 1][ar] = raw.y;
            As[ac4 + 2][ar] = raw.z;
            As[ac4 + 3][ar] = raw.w;
        }
#pragma unroll
        for (int i = 0; i < 4; i++) {
            int kk = bk + (i << 2);
            Bs[kk][bn] = W1[(size_t)(k0 + kk) * KU_N + n0 + bn];
        }
        __syncthreads();
#pragma unroll
        for (int kk = 0; kk < 16; kk++) {
            float4 a0 = *(const float4*)&As[kk][ty * 8];
            float4 a1 = *(const float4*)&As[kk][ty * 8 + 4];
            float4 bv = *(const float4*)&Bs[kk][tx * 4];
            float av[8] = {a0.x, a0.y, a0.z, a0.w, a1.x, a1.y, a1.z, a1.w};
            float bw[4] = {bv.x, bv.y, bv.z, bv.w};
#pragma unroll
            for (int r = 0; r < 8; r++)
#pragma unroll
                for (int c = 0; c < 4; c++) acc[r][c] += av[r] * bw[c];
        }
        __syncthreads();
    }
#pragma unroll
    for (int r = 0; r < 8; r++) {
        int m = m0 + ty * 8 + r;
#pragma unroll
        for (int c = 0; c < 4; c++) {
            int n = n0 + tx * 4 + c;
            KU[(size_t)m * KU_N + n] = acc[r][c] + b1[n];
        }
    }
}

// ---------------- persistent scan: 1 WG per 1 batch elem, all 64 steps ----------------
// 512 blocks x 448 thr (7 waves) -> 2 blocks/CU so barriers of one block overlap
// with compute of the other. 6 barriers/step (was 10). q-GEMM replaced by
// wt = Wq @ k1 (since s[n] = (h[n]·Wq)·k1 = h[n]·(Wq@k1)).

__global__ __launch_bounds__(448) void scan_kernel(
    const float* __restrict__ hidden, const float* __restrict__ masks,
    const float* __restrict__ Wq, const float* __restrict__ Wh,
    const float* __restrict__ grub, const float* __restrict__ Wq2,
    const float* __restrict__ Wk2, const float* __restrict__ Wv2,
    const float* __restrict__ KU, bf16_t* __restrict__ outb,
    float* __restrict__ hT_out, float* __restrict__ bm_out) {
    __shared__ float h[NHID];
    __shared__ float u[300];
    __shared__ float k1s[DK];
    __shared__ float wt[BSZ];          // Wq @ k1
    __shared__ float p1s[NBLK], bmv[NBLK];
    __shared__ float hg[NBLK][300];    // hg, then hn in cols [0,100)
    __shared__ float qkv[NBLK][164];   // q2|k2|v2
    __shared__ float p2s[NBLK][6];

    const int tid = threadIdx.x;
    const int b = blockIdx.x;

    // prologue: load h pre-masked for t=0, load KU row for t=0
    {
        float mv0 = masks[b];
        for (int j = tid; j < NHID; j += 448) h[j] = hidden[(size_t)b * NHID + j] * mv0;
        const float* kur = KU + (size_t)b * KU_N;
        for (int c = tid; c < 364; c += 448) {
            float v = kur[c];
            if (c < DK) k1s[c] = v; else u[c - DK] = v;
        }
    }
    __syncthreads();

    for (int t = 0; t < T_STEPS; t++) {
        // ---- p1: hg = hb @ Wh (items 0..299) + wt = Wq @ k1 (items 300..399)
        for (int idx = tid; idx < 400; idx += 448) {
            if (idx < 300) {
                int c = idx;
                float acc[NBLK] = {};
                for (int k = 0; k < BSZ; k += 4) {
                    float w0 = Wh[(k)*300 + c];
                    float w1 = Wh[(k + 1) * 300 + c];
                    float w2 = Wh[(k + 2) * 300 + c];
                    float w3 = Wh[(k + 3) * 300 + c];
#pragma unroll
                    for (int n = 0; n < NBLK; n++) {
                        float4 h4 = *(const float4*)&h[n * BSZ + k];
                        acc[n] += h4.x * w0 + h4.y * w1 + h4.z * w2 + h4.w * w3;
                    }
                }
#pragma unroll
                for (int n = 0; n < NBLK; n++) hg[n][c] = acc[n];
            } else {
                int kq = idx - 300;
                const float* wq = Wq + kq * DK;
                float acc = 0.f;
                for (int d = 0; d < DK; d += 4) {
                    float4 wv = *(const float4*)(wq + d);
                    float4 kv = *(const float4*)&k1s[d];
                    acc += wv.x * kv.x + wv.y * kv.y + wv.z * kv.z + wv.w * kv.w;
                }
                wt[kq] = acc;
            }
        }
        __syncthreads();
        // ---- p2: s[n] = h[n]·wt, p1 = sigmoid(s/8). 6 groups of 32 lanes.
        if (tid < 192) {
            int n = tid >> 5, l = tid & 31;
            float part = 0.f;
            if (l < 25) {
                float4 h4 = *(const float4*)&h[n * BSZ + l * 4];
                float4 w4 = *(const float4*)&wt[l * 4];
                part = h4.x * w4.x + h4.y * w4.y + h4.z * w4.z + h4.w * w4.w;
            }
            part += __shfl_down(part, 16, 32);
            part += __shfl_down(part, 8, 32);
            part += __shfl_down(part, 4, 32);
            part += __shfl_down(part, 2, 32);
            part += __shfl_down(part, 1, 32);
            if (l == 0) {
                float s = part * 0.125f;
                float mx = fmaxf(s, 0.f);
                float e0 = expf(0.f - mx), e1 = expf(s - mx);
                p1s[n] = e1 / (e0 + e1);
            }
        }
        __syncthreads();
        // ---- p3: GRU -> hn (items 0..599, written into hg cols [0,100)) + bmask (600..605)
        for (int idx = tid; idx < 606; idx += 448) {
            if (idx < 600) {
                int n = idx / BSZ, c = idx % BSZ;
                float p1 = p1s[n];
                float xr = p1 * u[c] + grub[c];
                float xz = p1 * u[BSZ + c] + grub[BSZ + c];
                float xn = p1 * u[2 * BSZ + c] + grub[2 * BSZ + c];
                float hr = hg[n][c], hz = hg[n][BSZ + c], hnn = hg[n][2 * BSZ + c];
                float r_ = 1.f / (1.f + expf(-(xr + hr)));
                float z_ = 1.f / (1.f + expf(-(xz + hz)));
                float nn = tanhf(xn + r_ * hnn);
                float hold = h[idx];
                hg[n][c] = (1.f - z_) * nn + z_ * hold;
            } else {
                int n = idx - 600;
                float pn = p1s[n];
                int cnt = 0;
                for (int j = 0; j < NBLK; j++) {
                    float pj = p1s[j];
                    if (pj > pn || (pj == pn && j < n)) cnt++;
                }
                float bm = (cnt < 4) ? 1.f : 0.f;
                bmv[n] = bm;
                bm_out[(size_t)(t * BATCH + b) * NBLK + n] = bm;
            }
        }
        __syncthreads();
        // ---- p4: q2|k2 = hn @ [Wq2|Wk2]  (384 items, 1 acc each)
        for (int idx = tid; idx < 384; idx += 448) {
            int n = idx >> 6, c = idx & 63;
            const float* w = (c < 32) ? (Wq2 + c) : (Wk2 + (c - 32));
            float acc = 0.f;
            for (int k = 0; k < BSZ; k += 4) {
                float4 h4 = *(const float4*)&hg[n][k];
                acc += h4.x * w[(k)*32] + h4.y * w[(k + 1) * 32] +
                       h4.z * w[(k + 2) * 32] + h4.w * w[(k + 3) * 32];
            }
            qkv[n][c] = acc;   // q2 at [0,32), k2 at [32,64)
        }
        __syncthreads();
        // ---- p5: wave 0: p2 logits+softmax (shfl, no extra barrier)
        //          waves 1..6: v2 = hn @ Wv2 (200 items x 3 accs)
        if (tid < 64) {
            if (tid < 36) {
                int n = tid / 6;
                int m = tid - n * 6;
                float e = 0.f;
                for (int d = 0; d < DC; d += 4) {
                    float4 q4 = *(const float4*)&qkv[n][d];
                    float4 k4 = *(const float4*)&qkv[m][32 + d];
                    e += q4.x * k4.x + q4.y * k4.y + q4.z * k4.z + q4.w * k4.w;
                }
                e *= 0.17677669529663687f;  // 1/sqrt(32)
                float ev[6];
#pragma unroll
                for (int j = 0; j < 6; j++) ev[j] = __shfl(e, n * 6 + j, 64);
                float mx = ev[0];
#pragma unroll
                for (int j = 1; j < 6; j++) mx = fmaxf(mx, ev[j]);
                float sum = 0.f;
#pragma unroll
                for (int j = 0; j < 6; j++) sum += expf(ev[j] - mx);
                p2s[n][m] = expf(e - mx) / sum;
            }
        } else {
            int idx = tid - 64;
            if (idx < 200) {
                int nb = (idx / 100) * 3, c = idx % 100;
                float a0 = 0.f, a1 = 0.f, a2 = 0.f;
                for (int k = 0; k < BSZ; k += 4) {
                    float w0 = Wv2[(k)*100 + c];
                    float w1 = Wv2[(k + 1) * 100 + c];
                    float w2 = Wv2[(k + 2) * 100 + c];
                    float w3 = Wv2[(k + 3) * 100 + c];
                    float4 h0 = *(const float4*)&hg[nb][k];
                    float4 h1 = *(const float4*)&hg[nb + 1][k];
                    float4 h2 = *(const float4*)&hg[nb + 2][k];
                    a0 += h0.x * w0 + h0.y * w1 + h0.z * w2 + h0.w * w3;
                    a1 += h1.x * w0 + h1.y * w1 + h1.z * w2 + h1.w * w3;
                    a2 += h2.x * w0 + h2.y * w1 + h2.z * w2 + h2.w * w3;
                }
                qkv[nb][64 + c] = a0;
                qkv[nb + 1][64 + c] = a1;
                qkv[nb + 2][64 + c] = a2;
            }
        }
        __syncthreads();
        // ---- p6: blend + writes; fold next-step mask into h; load next KU row
        float mv_next = (t < T_STEPS - 1) ? masks[(t + 1) * BATCH + b] : 1.f;
        size_t row = (size_t)(t * BATCH + b);
        for (int idx = tid; idx < 608; idx += 448) {
            if (idx < 600) {
                int n = idx / BSZ, c = idx % BSZ;
                float acc = hg[n][c];
#pragma unroll
                for (int m = 0; m < 6; m++) acc += p2s[n][m] * qkv[m][64 + c];
                float hold = h[idx];
                float hnew = (bmv[n] != 0.f) ? acc : hold;
                h[idx] = hnew * mv_next;
                outb[row * OUT_KP + idx] = (bf16_t)hnew;
                if (t == T_STEPS - 1) hT_out[(size_t)b * NHID + idx] = hnew;
            } else {
                outb[row * OUT_KP + NHID + (idx - 600)] = (bf16_t)0.f;
            }
        }
        if (t < T_STEPS - 1) {
            const float* kur = KU + (size_t)((t + 1) * BATCH + b) * KU_N;
            for (int c = tid; c < 364; c += 448) {
                float v = kur[c];
                if (c < DK) k1s[c] = v; else u[c - DK] = v;
            }
        }
        __syncthreads();
    }
}

// ---------------- dec = outb @ decWT^T + dec_b (bf16 MFMA 16x16x32) ----------------
// M=32768 N=512 K=608. BM=128 BN=64 BK=32, 4 waves; wave: 2 m-tiles x 4 n-tiles.

__global__ __launch_bounds__(256) void dec_gemm(const bf16_t* __restrict__ Ag,
                                                const bf16_t* __restrict__ Bg,
                                                const float* __restrict__ bias,
                                                float* __restrict__ C) {
    __shared__ bf16_t As[128][32];
    __shared__ bf16_t Bs[64][32];
    const int tid = threadIdx.x;
    const int wave = tid >> 6, lane = tid & 63;
    const int m0 = blockIdx.x * 128, n0 = blockIdx.y * 64;
    f32x4 acc[2][4] = {};
    for (int k0 = 0; k0 < OUT_KP; k0 += 32) {
#pragma unroll
        for (int ii = 0; ii < 2; ii++) {
            int el = (tid + ii * 256) * 8;
            int row = el >> 5, col = el & 31;
            *(float4*)&As[row][col] = *(const float4*)(Ag + (size_t)(m0 + row) * OUT_KP + k0 + col);
        }
        {
            int el = tid * 8;
            int row = el >> 5, col = el & 31;
            *(float4*)&Bs[row][col] = *(const float4*)(Bg + (size_t)(n0 + row) * OUT_KP + k0 + col);
        }
        __syncthreads();
        const int fm = lane & 15, fq = (lane >> 4) * 8;
        bf16x8 a[2], bfr[4];
        a[0] = *(const bf16x8*)&As[wave * 32 + fm][fq];
        a[1] = *(const bf16x8*)&As[wave * 32 + 16 + fm][fq];
#pragma unroll
        for (int nt = 0; nt < 4; nt++) bfr[nt] = *(const bf16x8*)&Bs[nt * 16 + fm][fq];
#pragma unroll
        for (int mt = 0; mt < 2; mt++)
#pragma unroll
            for (int nt = 0; nt < 4; nt++)
                acc[mt][nt] = __builtin_amdgcn_mfma_f32_16x16x32_bf16(a[mt], bfr[nt], acc[mt][nt], 0, 0, 0);
        __syncthreads();
    }
    const int fm = lane & 15, fr = (lane >> 4) * 4;
#pragma unroll
    for (int mt = 0; mt < 2; mt++)
#pragma unroll
        for (int nt = 0; nt < 4; nt++) {
            int n = n0 + nt * 16 + fm;
            float bia = bias[n];
#pragma unroll
            for (int r = 0; r < 4; r++) {
                int m = m0 + wave * 32 + mt * 16 + fr + r;
                C[(size_t)m * NTOKC + n] = acc[mt][nt][r] + bia;
            }
        }
}

// ---------------- launch ----------------

extern "C" void kernel_launch(void* const* d_in, const int* in_sizes, int n_in,
                              void* d_out, int out_size, void* d_ws, size_t ws_size,
                              hipStream_t stream) {
    const float* input  = (const float*)d_in[0];
    const float* hidden = (const float*)d_in[1];
    const float* masks  = (const float*)d_in[2];
    const float* encW   = (const float*)d_in[3];
    const float* encB   = (const float*)d_in[4];
    const float* Wq     = (const float*)d_in[5];
    const float* Wk     = (const float*)d_in[6];
    const float* Wv     = (const float*)d_in[7];
    const float* Wx     = (const float*)d_in[8];
    const float* Wh     = (const float*)d_in[9];
    const float* grub   = (const float*)d_in[10];
    const float* Wq2    = (const float*)d_in[11];
    const float* Wk2    = (const float*)d_in[12];
    const float* Wv2    = (const float*)d_in[13];
    const float* decW   = (const float*)d_in[14];
    const float* decB   = (const float*)d_in[15];

    char* ws = (char*)d_ws;
    float*  KU    = (float*)(ws + WS_KU);
    bf16_t* outb  = (bf16_t*)(ws + WS_OUTB);
    float*  W1    = (float*)(ws + WS_W1);
    float*  b1    = (float*)(ws + WS_B1);
    float*  WvWx  = (float*)(ws + WS_WVWX);
    bf16_t* decWT = (bf16_t*)(ws + WS_DECWT);

    float* out_dec = (float*)d_out;
    float* out_hT  = out_dec + 16777216;   // T*B*NTOK
    float* out_bm  = out_dec + 17084416;   // + B*NHID

    prep_wvwx<<<(NINP * 300 + 255) / 256, 256, 0, stream>>>(Wv, Wx, WvWx);
    prep_w1<<<(NTOKC * KU_N + 255) / 256, 256, 0, stream>>>(encW, Wk, WvWx, W1);
    prep_b1<<<2, 256, 0, stream>>>(encB, Wk, WvWx, b1);
    prep_decwt<<<(NTOKC * OUT_KP + 255) / 256, 256, 0, stream>>>(decW, decWT);
    ku_gemm<<<dim3(256, 6), 256, 0, stream>>>(input, W1, b1, KU);
    scan_kernel<<<512, 448, 0, stream>>>(hidden, masks, Wq, Wh, grub, Wq2, Wk2, Wv2,
                                         KU, outb, out_hT, out_bm);
    dec_gemm<<<dim3(256, 8), 256, 0, stream>>>(outb, decWT, decB, out_dec);
}

// Round 2
// 4154.009 us; speedup vs baseline: 1.3253x; 1.3253x over previous
//
#include <hip/hip_runtime.h>
#include <hip/hip_bf16.h>
#include <stdint.h>

typedef __bf16 bf16_t;
typedef __bf16 bf16x8 __attribute__((ext_vector_type(8)));
typedef float f32x4 __attribute__((ext_vector_type(4)));

#define T_STEPS 64
#define BATCH   512
#define NTOKC   512
#define NINP    600
#define NHID    600
#define NBLK    6
#define BSZ     100
#define DK      64
#define ATTD    340
#define DC      32
#define KU_N    384     // 64 (k1) + 300 (u) + pad
#define OUT_KP  608     // NHID padded for dec GEMM K

// workspace layout (bytes), all 16B aligned
#define WS_KU     0u                 // 32768*384*4  = 50331648
#define WS_OUTB   50331648u          // 32768*608*2  = 39845888
#define WS_W1     90177536u          // 512*384*4    = 786432
#define WS_B1     90963968u          // 384*4        = 1536
#define WS_WVWX   90965504u          // 600*300*4    = 720000
#define WS_DECWT  91685504u          // 512*608*2    = 622592  (end ~92.3 MB)

// ---------------- prep kernels (tiny fp32 GEMMs) ----------------

__global__ void prep_wvwx(const float* __restrict__ Wv, const float* __restrict__ Wx,
                          float* __restrict__ WvWx) {
    int idx = blockIdx.x * 256 + threadIdx.x;
    if (idx >= NINP * 300) return;
    int i = idx / 300, c = idx % 300;
    float acc = 0.f;
    for (int a = 0; a < ATTD; a++) acc += Wv[i * ATTD + a] * Wx[a * 300 + c];
    WvWx[i * 300 + c] = acc;
}

__global__ void prep_w1(const float* __restrict__ encW, const float* __restrict__ Wk,
                        const float* __restrict__ WvWx, float* __restrict__ W1) {
    int idx = blockIdx.x * 256 + threadIdx.x;
    if (idx >= NTOKC * KU_N) return;
    int i = idx / KU_N, c = idx % KU_N;
    float acc = 0.f;
    if (c < DK) {
        for (int k = 0; k < NINP; k++) acc += encW[i * NINP + k] * Wk[k * DK + c];
    } else if (c < DK + 300) {
        int cc = c - DK;
        for (int k = 0; k < NINP; k++) acc += encW[i * NINP + k] * WvWx[k * 300 + cc];
    }
    W1[idx] = acc;
}

__global__ void prep_b1(const float* __restrict__ encB, const float* __restrict__ Wk,
                        const float* __restrict__ WvWx, float* __restrict__ b1) {
    int c = blockIdx.x * 256 + threadIdx.x;
    if (c >= KU_N) return;
    float acc = 0.f;
    if (c < DK) {
        for (int k = 0; k < NINP; k++) acc += encB[k] * Wk[k * DK + c];
    } else if (c < DK + 300) {
        int cc = c - DK;
        for (int k = 0; k < NINP; k++) acc += encB[k] * WvWx[k * 300 + cc];
    }
    b1[c] = acc;
}

__global__ void prep_decwt(const float* __restrict__ decW, bf16_t* __restrict__ decWT) {
    int idx = blockIdx.x * 256 + threadIdx.x;
    if (idx >= NTOKC * OUT_KP) return;
    int n = idx / OUT_KP, k = idx % OUT_KP;
    decWT[idx] = (k < NHID) ? (bf16_t)decW[k * NTOKC + n] : (bf16_t)0.f;
}

// ---------------- KU = input @ W1 + b1 (fp32; precision-critical) ----------------
// M=32768, K=512, N=384. BM=128 BN=64 BK=16, 256 thr, 8x4 per-thread tile.

__global__ __launch_bounds__(256) void ku_gemm(const float* __restrict__ A,
                                               const float* __restrict__ W1,
                                               const float* __restrict__ b1,
                                               float* __restrict__ KU) {
    __shared__ float As[16][128];
    __shared__ float Bs[16][64];
    const int tid = threadIdx.x;
    const int m0 = blockIdx.x * 128, n0 = blockIdx.y * 64;
    const int ty = tid >> 4, tx = tid & 15;
    const int bk = tid >> 6, bn = tid & 63;
    float acc[8][4] = {};
    for (int k0 = 0; k0 < NTOKC; k0 += 16) {
#pragma unroll
        for (int ii = 0; ii < 2; ii++) {
            int t2 = tid + ii * 256;
            int ar = t2 >> 2, ac4 = (t2 & 3) << 2;
            float4 raw = *(const float4*)(A + (size_t)(m0 + ar) * NTOKC + k0 + ac4);
            As[ac4 + 0][ar] = raw.x;
            As[ac4 + 1][ar] = raw.y;
            As[ac4 + 2][ar] = raw.z;
            As[ac4 + 3][ar] = raw.w;
        }
#pragma unroll
        for (int i = 0; i < 4; i++) {
            int kk = bk + (i << 2);
            Bs[kk][bn] = W1[(size_t)(k0 + kk) * KU_N + n0 + bn];
        }
        __syncthreads();
#pragma unroll
        for (int kk = 0; kk < 16; kk++) {
            float4 a0 = *(const float4*)&As[kk][ty * 8];
            float4 a1 = *(const float4*)&As[kk][ty * 8 + 4];
            float4 bv = *(const float4*)&Bs[kk][tx * 4];
            float av[8] = {a0.x, a0.y, a0.z, a0.w, a1.x, a1.y, a1.z, a1.w};
            float bw[4] = {bv.x, bv.y, bv.z, bv.w};
#pragma unroll
            for (int r = 0; r < 8; r++)
#pragma unroll
                for (int c = 0; c < 4; c++) acc[r][c] += av[r] * bw[c];
        }
        __syncthreads();
    }
#pragma unroll
    for (int r = 0; r < 8; r++) {
        int m = m0 + ty * 8 + r;
#pragma unroll
        for (int c = 0; c < 4; c++) {
            int n = n0 + tx * 4 + c;
            KU[(size_t)m * KU_N + n] = acc[r][c] + b1[n];
        }
    }
}

// ---------------- persistent scan: 1 WG per batch elem, 384 thr, all 64 steps ----------------
// 512 blocks -> 2 blocks/CU so barrier drains of one block overlap with compute of
// the other. Phase bodies kept in the round-0 (VGPR=44) code shape: separate simple
// loops, no merged branchy strided mega-loops (round-1 regression: VGPR 128 +
// 475 MB of compiler-generated memory traffic).

__global__ __launch_bounds__(384, 4) void scan_kernel(
    const float* __restrict__ hidden, const float* __restrict__ masks,
    const float* __restrict__ Wq, const float* __restrict__ Wh,
    const float* __restrict__ grub, const float* __restrict__ Wq2,
    const float* __restrict__ Wk2, const float* __restrict__ Wv2,
    const float* __restrict__ KU, bf16_t* __restrict__ outb,
    float* __restrict__ hT_out, float* __restrict__ bm_out) {
    __shared__ float h[NHID];
    __shared__ float u[300];
    __shared__ float k1s[DK];
    __shared__ float wt[BSZ];          // Wq @ k1
    __shared__ float p1s[NBLK], bmv[NBLK];
    __shared__ float hg[NBLK][300];    // hg, then hn in cols [0,100)
    __shared__ float qkv[NBLK][164];   // q2|k2|v2
    __shared__ float p2s[NBLK][6];

    const int tid = threadIdx.x;
    const int b = blockIdx.x;

    // prologue: load h pre-masked for t=0, load KU row for t=0
    {
        float mv0 = masks[b];
        for (int j = tid; j < NHID; j += 384) h[j] = hidden[(size_t)b * NHID + j] * mv0;
        const float* kur = KU + (size_t)b * KU_N;
        for (int c = tid; c < 364; c += 384) {
            float v = kur[c];
            if (c < DK) k1s[c] = v; else u[c - DK] = v;
        }
    }
    __syncthreads();

    for (int t = 0; t < T_STEPS; t++) {
        // ---- p1: hg = h @ Wh (tids 0..299, 6 accs each); wt = Wq@k1 (tids 300..383)
        if (tid < 300) {
            const int c = tid;
            float acc[NBLK] = {};
            for (int k = 0; k < BSZ; k += 4) {
                float w0 = Wh[(k)*300 + c];
                float w1 = Wh[(k + 1) * 300 + c];
                float w2 = Wh[(k + 2) * 300 + c];
                float w3 = Wh[(k + 3) * 300 + c];
#pragma unroll
                for (int n = 0; n < NBLK; n++) {
                    float4 h4 = *(const float4*)&h[n * BSZ + k];
                    acc[n] += h4.x * w0 + h4.y * w1 + h4.z * w2 + h4.w * w3;
                }
            }
#pragma unroll
            for (int n = 0; n < NBLK; n++) hg[n][c] = acc[n];
        } else {
            for (int kq = tid - 300; kq < BSZ; kq += 84) {
                const float* wq = Wq + kq * DK;
                float acc = 0.f;
                for (int d = 0; d < DK; d += 4) {
                    float4 wv = *(const float4*)(wq + d);
                    float4 kv = *(const float4*)&k1s[d];
                    acc += wv.x * kv.x + wv.y * kv.y + wv.z * kv.z + wv.w * kv.w;
                }
                wt[kq] = acc;
            }
        }
        __syncthreads();
        // ---- p2: s[n] = h[n]·wt, p1 = sigmoid(s/8). 6 groups of 32 lanes.
        if (tid < 192) {
            int n = tid >> 5, l = tid & 31;
            float part = 0.f;
            if (l < 25) {
                float4 h4 = *(const float4*)&h[n * BSZ + l * 4];
                float4 w4 = *(const float4*)&wt[l * 4];
                part = h4.x * w4.x + h4.y * w4.y + h4.z * w4.z + h4.w * w4.w;
            }
            part += __shfl_down(part, 16, 32);
            part += __shfl_down(part, 8, 32);
            part += __shfl_down(part, 4, 32);
            part += __shfl_down(part, 2, 32);
            part += __shfl_down(part, 1, 32);
            if (l == 0) {
                float s = part * 0.125f;
                float mx = fmaxf(s, 0.f);
                float e0 = expf(0.f - mx), e1 = expf(s - mx);
                p1s[n] = e1 / (e0 + e1);
            }
        }
        __syncthreads();
        // ---- p3: GRU -> hn (600 items, hn into hg cols [0,100)); then top-4 rank
        for (int idx = tid; idx < 600; idx += 384) {
            int n = idx / BSZ, c = idx % BSZ;
            float p1 = p1s[n];
            float xr = p1 * u[c] + grub[c];
            float xz = p1 * u[BSZ + c] + grub[BSZ + c];
            float xn = p1 * u[2 * BSZ + c] + grub[2 * BSZ + c];
            float hr = hg[n][c], hz = hg[n][BSZ + c], hnn = hg[n][2 * BSZ + c];
            float r_ = 1.f / (1.f + expf(-(xr + hr)));
            float z_ = 1.f / (1.f + expf(-(xz + hz)));
            float nn = tanhf(xn + r_ * hnn);
            float hold = h[idx];
            hg[n][c] = (1.f - z_) * nn + z_ * hold;
        }
        if (tid < NBLK) {
            int n = tid;
            float pn = p1s[n];
            int cnt = 0;
            for (int j = 0; j < NBLK; j++) {
                float pj = p1s[j];
                if (pj > pn || (pj == pn && j < n)) cnt++;
            }
            float bm = (cnt < 4) ? 1.f : 0.f;
            bmv[n] = bm;
            bm_out[(size_t)(t * BATCH + b) * NBLK + n] = bm;
        }
        __syncthreads();
        // ---- p4: q2|k2 = hn @ [Wq2|Wk2]  (384 items, 1 acc each)
        {
            int n = tid >> 6, c = tid & 63;
            const float* w = (c < 32) ? (Wq2 + c) : (Wk2 + (c - 32));
            float acc = 0.f;
            for (int k = 0; k < BSZ; k += 4) {
                float4 h4 = *(const float4*)&hg[n][k];
                acc += h4.x * w[(k)*32] + h4.y * w[(k + 1) * 32] +
                       h4.z * w[(k + 2) * 32] + h4.w * w[(k + 3) * 32];
            }
            qkv[n][c] = acc;   // q2 at [0,32), k2 at [32,64)
        }
        __syncthreads();
        // ---- p5: wave 0 (lanes<36): p2 logits+softmax via shfl;
        //          tids 64..263: v2 = hn @ Wv2 (200 items x 3 accs)
        if (tid < 64) {
            if (tid < 36) {
                int n = tid / 6;
                int m = tid - n * 6;
                float e = 0.f;
                for (int d = 0; d < DC; d += 4) {
                    float4 q4 = *(const float4*)&qkv[n][d];
                    float4 k4 = *(const float4*)&qkv[m][32 + d];
                    e += q4.x * k4.x + q4.y * k4.y + q4.z * k4.z + q4.w * k4.w;
                }
                e *= 0.17677669529663687f;  // 1/sqrt(32)
                float ev[6];
#pragma unroll
                for (int j = 0; j < 6; j++) ev[j] = __shfl(e, n * 6 + j, 64);
                float mx = ev[0];
#pragma unroll
                for (int j = 1; j < 6; j++) mx = fmaxf(mx, ev[j]);
                float sum = 0.f;
#pragma unroll
                for (int j = 0; j < 6; j++) sum += expf(ev[j] - mx);
                p2s[n][m] = expf(e - mx) / sum;
            }
        } else if (tid < 264) {
            int idx = tid - 64;
            int nb = (idx / 100) * 3, c = idx % 100;
            float a0 = 0.f, a1 = 0.f, a2 = 0.f;
            for (int k = 0; k < BSZ; k += 4) {
                float w0 = Wv2[(k)*100 + c];
                float w1 = Wv2[(k + 1) * 100 + c];
                float w2 = Wv2[(k + 2) * 100 + c];
                float w3 = Wv2[(k + 3) * 100 + c];
                float4 h0 = *(const float4*)&hg[nb][k];
                float4 h1 = *(const float4*)&hg[nb + 1][k];
                float4 h2 = *(const float4*)&hg[nb + 2][k];
                a0 += h0.x * w0 + h0.y * w1 + h0.z * w2 + h0.w * w3;
                a1 += h1.x * w0 + h1.y * w1 + h1.z * w2 + h1.w * w3;
                a2 += h2.x * w0 + h2.y * w1 + h2.z * w2 + h2.w * w3;
            }
            qkv[nb][64 + c] = a0;
            qkv[nb + 1][64 + c] = a1;
            qkv[nb + 2][64 + c] = a2;
        }
        __syncthreads();
        // ---- p6: blend + writes; fold next-step mask into h; prefetch next KU row
        {
            float mv_next = (t < T_STEPS - 1) ? masks[(t + 1) * BATCH + b] : 1.f;
            size_t row = (size_t)(t * BATCH + b);
            for (int idx = tid; idx < 600; idx += 384) {
                int n = idx / BSZ, c = idx % BSZ;
                float acc = hg[n][c];
#pragma unroll
                for (int m = 0; m < 6; m++) acc += p2s[n][m] * qkv[m][64 + c];
                float hold = h[idx];
                float hnew = (bmv[n] != 0.f) ? acc : hold;
                h[idx] = hnew * mv_next;
                outb[row * OUT_KP + idx] = (bf16_t)hnew;
                if (t == T_STEPS - 1) hT_out[(size_t)b * NHID + idx] = hnew;
            }
            if (tid < 8) outb[row * OUT_KP + NHID + tid] = (bf16_t)0.f;
            if (t < T_STEPS - 1) {
                const float* kur = KU + (size_t)((t + 1) * BATCH + b) * KU_N;
                for (int c = tid; c < 364; c += 384) {
                    float v = kur[c];
                    if (c < DK) k1s[c] = v; else u[c - DK] = v;
                }
            }
        }
        __syncthreads();
    }
}

// ---------------- dec = outb @ decWT^T + dec_b (bf16 MFMA 16x16x32) ----------------
// M=32768 N=512 K=608. BM=128 BN=64 BK=32, 4 waves; wave: 2 m-tiles x 4 n-tiles.

__global__ __launch_bounds__(256) void dec_gemm(const bf16_t* __restrict__ Ag,
                                                const bf16_t* __restrict__ Bg,
                                                const float* __restrict__ bias,
                                                float* __restrict__ C) {
    __shared__ bf16_t As[128][32];
    __shared__ bf16_t Bs[64][32];
    const int tid = threadIdx.x;
    const int wave = tid >> 6, lane = tid & 63;
    const int m0 = blockIdx.x * 128, n0 = blockIdx.y * 64;
    f32x4 acc[2][4] = {};
    for (int k0 = 0; k0 < OUT_KP; k0 += 32) {
#pragma unroll
        for (int ii = 0; ii < 2; ii++) {
            int el = (tid + ii * 256) * 8;
            int row = el >> 5, col = el & 31;
            *(float4*)&As[row][col] = *(const float4*)(Ag + (size_t)(m0 + row) * OUT_KP + k0 + col);
        }
        {
            int el = tid * 8;
            int row = el >> 5, col = el & 31;
            *(float4*)&Bs[row][col] = *(const float4*)(Bg + (size_t)(n0 + row) * OUT_KP + k0 + col);
        }
        __syncthreads();
        const int fm = lane & 15, fq = (lane >> 4) * 8;
        bf16x8 a[2], bfr[4];
        a[0] = *(const bf16x8*)&As[wave * 32 + fm][fq];
        a[1] = *(const bf16x8*)&As[wave * 32 + 16 + fm][fq];
#pragma unroll
        for (int nt = 0; nt < 4; nt++) bfr[nt] = *(const bf16x8*)&Bs[nt * 16 + fm][fq];
#pragma unroll
        for (int mt = 0; mt < 2; mt++)
#pragma unroll
            for (int nt = 0; nt < 4; nt++)
                acc[mt][nt] = __builtin_amdgcn_mfma_f32_16x16x32_bf16(a[mt], bfr[nt], acc[mt][nt], 0, 0, 0);
        __syncthreads();
    }
    const int fm = lane & 15, fr = (lane >> 4) * 4;
#pragma unroll
    for (int mt = 0; mt < 2; mt++)
#pragma unroll
        for (int nt = 0; nt < 4; nt++) {
            int n = n0 + nt * 16 + fm;
            float bia = bias[n];
#pragma unroll
            for (int r = 0; r < 4; r++) {
                int m = m0 + wave * 32 + mt * 16 + fr + r;
                C[(size_t)m * NTOKC + n] = acc[mt][nt][r] + bia;
            }
        }
}

// ---------------- launch ----------------

extern "C" void kernel_launch(void* const* d_in, const int* in_sizes, int n_in,
                              void* d_out, int out_size, void* d_ws, size_t ws_size,
                              hipStream_t stream) {
    const float* input  = (const float*)d_in[0];
    const float* hidden = (const float*)d_in[1];
    const float* masks  = (const float*)d_in[2];
    const float* encW   = (const float*)d_in[3];
    const float* encB   = (const float*)d_in[4];
    const float* Wq     = (const float*)d_in[5];
    const float* Wk     = (const float*)d_in[6];
    const float* Wv     = (const float*)d_in[7];
    const float* Wx     = (const float*)d_in[8];
    const float* Wh     = (const float*)d_in[9];
    const float* grub   = (const float*)d_in[10];
    const float* Wq2    = (const float*)d_in[11];
    const float* Wk2    = (const float*)d_in[12];
    const float* Wv2    = (const float*)d_in[13];
    const float* decW   = (const float*)d_in[14];
    const float* decB   = (const float*)d_in[15];

    char* ws = (char*)d_ws;
    float*  KU    = (float*)(ws + WS_KU);
    bf16_t* outb  = (bf16_t*)(ws + WS_OUTB);
    float*  W1    = (float*)(ws + WS_W1);
    float*  b1    = (float*)(ws + WS_B1);
    float*  WvWx  = (float*)(ws + WS_WVWX);
    bf16_t* decWT = (bf16_t*)(ws + WS_DECWT);

    float* out_dec = (float*)d_out;
    float* out_hT  = out_dec + 16777216;   // T*B*NTOK
    float* out_bm  = out_dec + 17084416;   // + B*NHID

    prep_wvwx<<<(NINP * 300 + 255) / 256, 256, 0, stream>>>(Wv, Wx, WvWx);
    prep_w1<<<(NTOKC * KU_N + 255) / 256, 256, 0, stream>>>(encW, Wk, WvWx, W1);
    prep_b1<<<2, 256, 0, stream>>>(encB, Wk, WvWx, b1);
    prep_decwt<<<(NTOKC * OUT_KP + 255) / 256, 256, 0, stream>>>(decW, decWT);
    ku_gemm<<<dim3(256, 6), 256, 0, stream>>>(input, W1, b1, KU);
    scan_kernel<<<512, 384, 0, stream>>>(hidden, masks, Wq, Wh, grub, Wq2, Wk2, Wv2,
                                         KU, outb, out_hT, out_bm);
    dec_gemm<<<dim3(256, 8), 256, 0, stream>>>(outb, decWT, decB, out_dec);
}